// Round 2
// baseline (609.473 us; speedup 1.0000x reference)
//
#include <hip/hip_runtime.h>
#include <stdint.h>

typedef __bf16 bf16;
typedef __bf16 bf16x8 __attribute__((ext_vector_type(8)));
typedef __bf16 bf16x4 __attribute__((ext_vector_type(4)));
typedef float  f32x4  __attribute__((ext_vector_type(4)));

#define KP 1088

// workspace byte offsets
#define WQ_OFF   0u          // bf16 [1024][1088]
#define RTH_OFF  2228224u    // bf16 [2][512][512]  R^T hi split
#define RTL_OFF  3276800u    // bf16 [2][512][512]  R^T lo split
#define S0_OFF   4325376u    // f32 [32768]
#define S1_OFF   4456448u    // f32 [32768]
#define XQ_OFF   4587520u    // bf16 [32768][1088]
// total: 75,890,688 bytes

typedef __attribute__((address_space(1))) void gvoid;
typedef __attribute__((address_space(3))) void lvoid;

__device__ __forceinline__ void async_ld16(const void* g, const void* l) {
  __builtin_amdgcn_global_load_lds((gvoid*)(uintptr_t)g,
                                   (lvoid*)(uint32_t)(uintptr_t)l, 16, 0, 0);
}

__device__ __forceinline__ int s4(int r) { return (r ^ (r >> 2)) & 3; }

// ---------- K0: transpose + split R0,R1 (fp32 -> bf16 hi/lo) ----------
__global__ __launch_bounds__(256) void k_rsplit(const float* __restrict__ R0,
    const float* __restrict__ R1, bf16* __restrict__ Rth, bf16* __restrict__ Rtl) {
  __shared__ float t[32][33];
  const float* src = blockIdx.z ? R1 : R0;
  bf16* dh = Rth + (size_t)blockIdx.z * 512 * 512;
  bf16* dl = Rtl + (size_t)blockIdx.z * 512 * 512;
  int k0 = blockIdx.x * 32, n0 = blockIdx.y * 32;
  int tx = threadIdx.x & 31, ty = threadIdx.x >> 5;
  #pragma unroll
  for (int j = 0; j < 32; j += 8)
    t[ty + j][tx] = src[(size_t)(k0 + ty + j) * 512 + n0 + tx];
  __syncthreads();
  #pragma unroll
  for (int j = 0; j < 32; j += 8) {
    float v = t[tx][ty + j];
    bf16 h = (bf16)v;
    bf16 l = (bf16)(v - (float)h);
    dh[(size_t)(n0 + ty + j) * 512 + k0 + tx] = h;
    dl[(size_t)(n0 + ty + j) * 512 + k0 + tx] = l;
  }
}

// ---------- K1: weight prep -> Wq [1024][1088] bf16 ----------
// cols [0,512)=q_w0 ints, [512,1024)=q_w1 ints, [1024,1056)=U, [1056,1088)=0
__global__ __launch_bounds__(256) void k_wprep(const float* __restrict__ w,
    const float* __restrict__ U, const float* __restrict__ V,
    const float* __restrict__ R0, const float* __restrict__ R1,
    const float* __restrict__ ws0, const float* __restrict__ ws1,
    bf16* __restrict__ Wq) {
  __shared__ float wres[4][1024];
  __shared__ float urow[4][32];
  const int o0 = blockIdx.x * 4;
  const int tid = threadIdx.x;
  if (tid < 128) { int i = tid >> 5, r = tid & 31; urow[i][r] = U[(o0 + i) * 32 + r]; }
  __syncthreads();
  for (int i = 0; i < 4; i++)
    for (int c = tid; c < 1024; c += 256) {
      float a = w[(size_t)(o0 + i) * 1024 + c];
      #pragma unroll
      for (int r = 0; r < 32; r++) a -= urow[i][r] * V[(size_t)r * 1024 + c];
      wres[i][c] = a;
    }
  __syncthreads();
  for (int half = 0; half < 2; half++) {
    const float* R = half ? R1 : R0;
    for (int j = 0; j < 2; j++) {
      int n = (j << 8) + tid;
      float acc[4] = {0.f, 0.f, 0.f, 0.f};
      for (int c = 0; c < 512; c++) {
        float rv = R[(size_t)c * 512 + n];
        #pragma unroll
        for (int i = 0; i < 4; i++) acc[i] += wres[i][half * 512 + c] * rv;
      }
      #pragma unroll
      for (int i = 0; i < 4; i++) {
        float wsv = half ? ws1[o0 + i] : ws0[o0 + i];
        float q = fminf(fmaxf(__builtin_rintf(acc[i] / wsv), -8.f), 7.f);
        Wq[(size_t)(o0 + i) * KP + half * 512 + n] = (bf16)q;
      }
    }
  }
  { int i = tid >> 6, c = tid & 63;
    bf16 v = (bf16)0.f;
    if (c < 32) v = (bf16)U[(o0 + i) * 32 + c];
    Wq[(size_t)(o0 + i) * KP + 1024 + c] = v; }
}

// ---------- K2: rotation (split-bf16, 3 products) + dynamic quant ----------
// block: 64 rows x full 512-col half; BK=32.
__global__ __launch_bounds__(512) void k_actq(const float* __restrict__ x,
    const bf16* __restrict__ Rth, const bf16* __restrict__ Rtl,
    float* __restrict__ s0, float* __restrict__ s1, bf16* __restrict__ Xq) {
  const int half = blockIdx.y;
  const bf16* BhG = Rth + (size_t)half * 512 * 512;
  const bf16* BlG = Rtl + (size_t)half * 512 * 512;
  float* sout = half ? s1 : s0;
  const int rowBase = blockIdx.x * 64;
  const int tid = threadIdx.x;
  const int wave = tid >> 6, lane = tid & 63, l15 = lane & 15, l4 = lane >> 4;
  __shared__ __align__(16) bf16 Ah[64 * 32];
  __shared__ __align__(16) bf16 Al[64 * 32];
  __shared__ __align__(16) bf16 Bbuf[2 * 512 * 32];
  __shared__ float red[8][64];
  __shared__ float sbuf[64];
  bf16* Bh = Bbuf;
  bf16* Bl = Bbuf + 512 * 32;

  f32x4 acc[4][4];
  #pragma unroll
  for (int mt = 0; mt < 4; mt++)
    #pragma unroll
    for (int nt = 0; nt < 4; nt++)
      #pragma unroll
      for (int r = 0; r < 4; r++) acc[mt][nt][r] = 0.f;

  const int arow = tid >> 3, ap = tid & 7;
  const int apos = (ap >> 1) ^ s4(arow);
  const int aoff = arow * 32 + apos * 8 + (ap & 1) * 4;

  for (int it = 0; it < 16; it++) {
    const int kk = it * 32;
    __syncthreads();
    // A chunk: fp32 global -> regs (coalesced float4)
    f32x4 av = *(const f32x4*)(x + (size_t)(rowBase + arow) * 1024 + half * 512 + kk + ap * 4);
    // B chunks: async global->LDS (hi & lo splits), XOR-swizzled on the global side
    #pragma unroll
    for (int i = 0; i < 4; i++) {
      int slot = i * 512 + tid;
      int n = slot >> 2, q = slot & 3;
      int c = q ^ s4(n);
      async_ld16(BhG + (size_t)n * 512 + kk + c * 8, Bh + slot * 8);
      async_ld16(BlG + (size_t)n * 512 + kk + c * 8, Bl + slot * 8);
    }
    // split-convert A and write to LDS
    bf16x4 hv, lv;
    #pragma unroll
    for (int j = 0; j < 4; j++) {
      float v = av[j];
      bf16 h = (bf16)v;
      hv[j] = h;
      lv[j] = (bf16)(v - (float)h);
    }
    *(bf16x4*)(Ah + aoff) = hv;
    *(bf16x4*)(Al + aoff) = lv;
    __syncthreads();
    // compute: acc += xh*Rh + xl*Rh + xh*Rl
    bf16x8 ah[4], al[4];
    #pragma unroll
    for (int mt = 0; mt < 4; mt++) {
      int m = mt * 16 + l15;
      int pos = l4 ^ s4(m);
      ah[mt] = *(const bf16x8*)(Ah + m * 32 + pos * 8);
      al[mt] = *(const bf16x8*)(Al + m * 32 + pos * 8);
    }
    #pragma unroll
    for (int nt = 0; nt < 4; nt++) {
      int n = wave * 64 + nt * 16 + l15;
      int pos = l4 ^ s4(n);
      bf16x8 bh = *(const bf16x8*)(Bh + n * 32 + pos * 8);
      bf16x8 bl = *(const bf16x8*)(Bl + n * 32 + pos * 8);
      #pragma unroll
      for (int mt = 0; mt < 4; mt++) {
        acc[mt][nt] = __builtin_amdgcn_mfma_f32_16x16x32_bf16(ah[mt], bh, acc[mt][nt], 0, 0, 0);
        acc[mt][nt] = __builtin_amdgcn_mfma_f32_16x16x32_bf16(al[mt], bh, acc[mt][nt], 0, 0, 0);
        acc[mt][nt] = __builtin_amdgcn_mfma_f32_16x16x32_bf16(ah[mt], bl, acc[mt][nt], 0, 0, 0);
      }
    }
  }
  // per-row absmax: in-lane over nt, shuffle over 16 col-lanes, LDS over 8 waves
  #pragma unroll
  for (int mt = 0; mt < 4; mt++)
    #pragma unroll
    for (int r = 0; r < 4; r++) {
      float v = 0.f;
      #pragma unroll
      for (int nt = 0; nt < 4; nt++) v = fmaxf(v, fabsf(acc[mt][nt][r]));
      v = fmaxf(v, __shfl_xor(v, 1));
      v = fmaxf(v, __shfl_xor(v, 2));
      v = fmaxf(v, __shfl_xor(v, 4));
      v = fmaxf(v, __shfl_xor(v, 8));
      if (l15 == 0) red[wave][mt * 16 + l4 * 4 + r] = v;
    }
  __syncthreads();
  if (tid < 64) {
    float m = red[0][tid];
    #pragma unroll
    for (int w2 = 1; w2 < 8; w2++) m = fmaxf(m, red[w2][tid]);
    float s = fmaxf(m / 7.0f, 1e-8f);
    sbuf[tid] = s;
    sout[rowBase + tid] = s;
  }
  __syncthreads();
  // quantize into LDS (reuse B buffer), then coalesced 16B stores
  #pragma unroll
  for (int mt = 0; mt < 4; mt++)
    #pragma unroll
    for (int r = 0; r < 4; r++) {
      int lrow = mt * 16 + l4 * 4 + r;
      float s = sbuf[lrow];
      #pragma unroll
      for (int nt = 0; nt < 4; nt++) {
        float q = fminf(fmaxf(__builtin_rintf(acc[mt][nt][r] / s), -8.f), 7.f);
        Bbuf[lrow * 512 + wave * 64 + nt * 16 + l15] = (bf16)q;
      }
    }
  __syncthreads();
  #pragma unroll
  for (int i = 0; i < 8; i++) {
    int slot = i * 512 + tid;
    int row = slot >> 6, c8 = slot & 63;
    *(bf16x8*)(Xq + (size_t)(rowBase + row) * KP + half * 512 + c8 * 8) =
        *(const bf16x8*)(Bbuf + row * 512 + c8 * 8);
  }
}

// ---------- K3: y = x @ V^T -> Xq[:,1024:1056], zeros [1056:1088) ----------
__global__ __launch_bounds__(256) void k_ygemm(const float* __restrict__ x,
    const float* __restrict__ V, bf16* __restrict__ Xq) {
  const int rowBase = blockIdx.x * 64;
  const int tid = threadIdx.x;
  const int wave = tid >> 6, lane = tid & 63, l15 = lane & 15, l4 = lane >> 4;
  __shared__ __align__(16) bf16 Ahs[64 * 32];
  __shared__ __align__(16) bf16 Bhs[32 * 32];
  f32x4 acc[2];
  #pragma unroll
  for (int nt = 0; nt < 2; nt++)
    #pragma unroll
    for (int r = 0; r < 4; r++) acc[nt][r] = 0.f;

  for (int it = 0; it < 32; it++) {
    const int kk = it * 32;
    __syncthreads();
    f32x4 av[2];
    #pragma unroll
    for (int i = 0; i < 2; i++) {
      int s = i * 256 + tid, row = s >> 3, p = s & 7;
      av[i] = *(const f32x4*)(x + (size_t)(rowBase + row) * 1024 + kk + p * 4);
    }
    int vn = tid >> 3, vp = tid & 7;
    f32x4 vv = *(const f32x4*)(V + (size_t)vn * 1024 + kk + vp * 4);
    #pragma unroll
    for (int i = 0; i < 2; i++) {
      int s = i * 256 + tid, row = s >> 3, p = s & 7;
      int pos = (p >> 1) ^ s4(row);
      bf16x4 hv;
      #pragma unroll
      for (int j = 0; j < 4; j++) hv[j] = (bf16)av[i][j];
      *(bf16x4*)(Ahs + row * 32 + pos * 8 + (p & 1) * 4) = hv;
    }
    { int pos = (vp >> 1) ^ s4(vn);
      bf16x4 hv;
      #pragma unroll
      for (int j = 0; j < 4; j++) hv[j] = (bf16)vv[j];
      *(bf16x4*)(Bhs + vn * 32 + pos * 8 + (vp & 1) * 4) = hv; }
    __syncthreads();
    int m = wave * 16 + l15;
    int posA = l4 ^ s4(m);
    bf16x8 a = *(const bf16x8*)(Ahs + m * 32 + posA * 8);
    #pragma unroll
    for (int nt = 0; nt < 2; nt++) {
      int n = nt * 16 + l15;
      int posB = l4 ^ s4(n);
      bf16x8 b = *(const bf16x8*)(Bhs + n * 32 + posB * 8);
      acc[nt] = __builtin_amdgcn_mfma_f32_16x16x32_bf16(a, b, acc[nt], 0, 0, 0);
    }
  }
  #pragma unroll
  for (int nt = 0; nt < 2; nt++)
    #pragma unroll
    for (int r = 0; r < 4; r++) {
      int row = rowBase + wave * 16 + l4 * 4 + r;
      Xq[(size_t)row * KP + 1024 + nt * 16 + l15] = (bf16)acc[nt][r];
    }
  { int row = rowBase + (tid >> 2), co = (tid & 3) * 8;
    bf16x8 z;
    #pragma unroll
    for (int j = 0; j < 8; j++) z[j] = (bf16)0.f;
    *(bf16x8*)(Xq + (size_t)row * KP + 1056 + co) = z; }
}

// ---------- K4: main fused GEMM, 128x128 tile, K=1088 segmented ----------
__global__ __launch_bounds__(256, 2) void k_main(const bf16* __restrict__ Xq,
    const bf16* __restrict__ Wq, const float* __restrict__ s0, const float* __restrict__ s1,
    const float* __restrict__ ws0, const float* __restrict__ ws1,
    const float* __restrict__ bias, const float* __restrict__ gamma,
    const float* __restrict__ beta, float* __restrict__ out) {
  const int tid = threadIdx.x;
  const int wave = tid >> 6, lane = tid & 63, l15 = lane & 15, l4 = lane >> 4;
  const int waveM = wave >> 1, waveN = wave & 1;
  // XCD-aware swizzle: the 8 col-blocks of one row-panel land on one XCD
  const int b = blockIdx.x;
  const int g = b & 7, t = b >> 3;
  const int rowBase = (g * 32 + (t >> 3)) * 128;
  const int colBase = (t & 7) * 128;
  __shared__ __align__(16) bf16 As[128 * 64];
  __shared__ __align__(16) bf16 Bs[128 * 64];
  f32x4 acc[4][4], res[4][4];
  #pragma unroll
  for (int mt = 0; mt < 4; mt++)
    #pragma unroll
    for (int nt = 0; nt < 4; nt++)
      #pragma unroll
      for (int r = 0; r < 4; r++) { acc[mt][nt][r] = 0.f; res[mt][nt][r] = 0.f; }

  auto stage = [&](int kk) {
    #pragma unroll
    for (int i = 0; i < 4; i++) {
      int slot = i * 256 + tid;
      int row = slot >> 3, cp = slot & 7;
      int c = cp ^ (row & 7);
      async_ld16(Xq + (size_t)(rowBase + row) * KP + kk + c * 8, As + slot * 8);
      async_ld16(Wq + (size_t)(colBase + row) * KP + kk + c * 8, Bs + slot * 8);
    }
  };
  auto compute = [&]() {
    #pragma unroll
    for (int ks = 0; ks < 2; ks++) {
      const int cb = ks * 4 + l4;
      bf16x8 a[4], bb[4];
      #pragma unroll
      for (int mt = 0; mt < 4; mt++) {
        int m = waveM * 64 + mt * 16 + l15;
        a[mt] = *(const bf16x8*)(As + (m * 8 + (cb ^ (m & 7))) * 8);
      }
      #pragma unroll
      for (int nt = 0; nt < 4; nt++) {
        int n = waveN * 64 + nt * 16 + l15;
        bb[nt] = *(const bf16x8*)(Bs + (n * 8 + (cb ^ (n & 7))) * 8);
      }
      #pragma unroll
      for (int mt = 0; mt < 4; mt++)
        #pragma unroll
        for (int nt = 0; nt < 4; nt++)
          acc[mt][nt] = __builtin_amdgcn_mfma_f32_16x16x32_bf16(a[mt], bb[nt], acc[mt][nt], 0, 0, 0);
    }
  };
  auto fold = [&](const float* srow, const float* wscol) {
    float sw[4];
    #pragma unroll
    for (int nt = 0; nt < 4; nt++) sw[nt] = wscol[colBase + waveN * 64 + nt * 16 + l15];
    #pragma unroll
    for (int mt = 0; mt < 4; mt++)
      #pragma unroll
      for (int r = 0; r < 4; r++) {
        float sr = srow[rowBase + waveM * 64 + mt * 16 + l4 * 4 + r];
        #pragma unroll
        for (int nt = 0; nt < 4; nt++) {
          res[mt][nt][r] += acc[mt][nt][r] * sr * sw[nt];
          acc[mt][nt][r] = 0.f;
        }
      }
  };

  for (int it = 0; it < 8; it++) { __syncthreads(); stage(it * 64); __syncthreads(); compute(); }
  fold(s0, ws0);
  for (int it = 8; it < 16; it++) { __syncthreads(); stage(it * 64); __syncthreads(); compute(); }
  fold(s1, ws1);
  __syncthreads(); stage(1024); __syncthreads(); compute();  // fp low-rank segment

  #pragma unroll
  for (int nt = 0; nt < 4; nt++) {
    int col = colBase + waveN * 64 + nt * 16 + l15;
    float bi = bias[col], ga = gamma[col], be = beta[col];
    #pragma unroll
    for (int mt = 0; mt < 4; mt++)
      #pragma unroll
      for (int r = 0; r < 4; r++) {
        int row = rowBase + waveM * 64 + mt * 16 + l4 * 4 + r;
        float v = (res[mt][nt][r] + acc[mt][nt][r] + bi) * ga + be;
        out[(size_t)row * 1024 + col] = v;
      }
  }
}

extern "C" void kernel_launch(void* const* d_in, const int* in_sizes, int n_in,
                              void* d_out, int out_size, void* d_ws, size_t ws_size,
                              hipStream_t stream) {
  const float* x     = (const float*)d_in[0];
  const float* w     = (const float*)d_in[1];
  const float* bias  = (const float*)d_in[2];
  const float* U     = (const float*)d_in[3];
  const float* V     = (const float*)d_in[4];
  const float* R0    = (const float*)d_in[5];
  const float* R1    = (const float*)d_in[6];
  const float* ws0   = (const float*)d_in[7];
  const float* ws1   = (const float*)d_in[8];
  const float* gamma = (const float*)d_in[9];
  const float* beta  = (const float*)d_in[10];
  char* wsb = (char*)d_ws;
  bf16*  Wq  = (bf16*)(wsb + WQ_OFF);
  bf16*  Rth = (bf16*)(wsb + RTH_OFF);
  bf16*  Rtl = (bf16*)(wsb + RTL_OFF);
  float* s0  = (float*)(wsb + S0_OFF);
  float* s1  = (float*)(wsb + S1_OFF);
  bf16*  Xq  = (bf16*)(wsb + XQ_OFF);
  float* out = (float*)d_out;

  k_rsplit<<<dim3(16, 16, 2), dim3(256), 0, stream>>>(R0, R1, Rth, Rtl);
  k_wprep<<<dim3(256), dim3(256), 0, stream>>>(w, U, V, R0, R1, ws0, ws1, Wq);
  k_actq<<<dim3(512, 2), dim3(512), 0, stream>>>(x, Rth, Rtl, s0, s1, Xq);
  k_ygemm<<<dim3(512), dim3(256), 0, stream>>>(x, V, Xq);
  k_main<<<dim3(2048), dim3(256), 0, stream>>>(Xq, Wq, s0, s1, ws0, ws1,
                                               bias, gamma, beta, out);
}